// Round 10
// baseline (74.316 us; speedup 1.0000x reference)
//
#include <hip/hip_runtime.h>
#include <hip/hip_bf16.h>

namespace {

constexpr int kHW = 36864;  // 192*192
constexpr int kRepackBlocks = 2304;  // 144 px-tiles x 8 ks x 2 b
constexpr int kGemmBlocks = 1152;    // 576 tiles x 2 b
constexpr int kFocalBlocks = 605;    // 7744 cells x 20 quads / 256

typedef __attribute__((ext_vector_type(8))) short bf16x8;
typedef __attribute__((ext_vector_type(4))) float f32x4;

__device__ __forceinline__ unsigned short f2bf(float x) {
  return __builtin_bit_cast(unsigned short, __float2bfloat16(x));
}

__device__ __forceinline__ float wave_sum(float v) {
#pragma unroll
  for (int off = 32; off; off >>= 1) v += __shfl_xor(v, off, 64);
  return v;
}

// ---------------------------------------------------------------------------
// K1: repack mask_out -> frag-ready bf16 moT, plus prep (zero acc, gather K).
//
// Repack block (bid < 2304) covers one (b, ks, 256-px tile): reads 32
// channel strips of 1 KB (one wave-instruction each, fully coalesced),
// transposes via LDS [32][524] bf16 (ds_write_b64 2-way free; u16 reads
// 4-way via the 1048B row stride), writes 1-KB coalesced frag chunks:
//   moT[((b*2304 + pxblk)*8 + ks)*512 + lane*8 + j]
// where lane = px16 + 16*kh encodes (pixel, k-half) exactly as the GEMM
// B-frag wants it. Prep blocks (bid >= 2304) zero acc / gather kbf rows.
// ---------------------------------------------------------------------------
__global__ __launch_bounds__(256, 4) void repack_prep_kernel(
    const float* __restrict__ mask_out,
    const float* __restrict__ k0, const float* __restrict__ k1,
    const float* __restrict__ k2, const float* __restrict__ k3,
    const float* __restrict__ k4,
    const int* __restrict__ q0, const int* __restrict__ q1,
    const int* __restrict__ q2, const int* __restrict__ q3,
    const int* __restrict__ q4,
    unsigned short* __restrict__ moT, unsigned short* __restrict__ kbf,
    float* __restrict__ acc) {
  const int bid = blockIdx.x;
  if (bid >= kRepackBlocks) {
    const int pid = bid - kRepackBlocks;
    if (pid == 0) {
      for (int i = threadIdx.x; i < 482; i += 256) acc[i] = 0.f;
      return;
    }
    const int idx = pid - 1;  // 0..159
    const int b = idx / 80;
    const int row = idx - b * 80;
    if (threadIdx.x >= 128) return;
    const int l = row >> 4, p = row & 15;
    const float* kb[5] = {k0, k1, k2, k3, k4};
    const int* pb[5] = {q0, q1, q2, q3, q4};
    const int bg2[5] = {b * 1600, b * 1296, b * 576, b * 256, b * 144};
    const int pos = pb[l][b * 16 + p];
    const int ch = threadIdx.x * 2;
    const float2 kv =
        *(const float2*)(kb[l] + (size_t)(bg2[l] + pos) * 256 + ch);
    *(unsigned int*)&kbf[((size_t)b * 80 + row) * 256 + ch] =
        (unsigned int)f2bf(kv.x) | ((unsigned int)f2bf(kv.y) << 16);
    return;
  }

  // ---- repack ----
  const int b = bid / 1152;
  const int rem = bid - b * 1152;
  const int ks = rem / 144;
  const int pxt = rem - ks * 144;  // 256-px tile index
  const int lane = threadIdx.x & 63;
  const int wv = threadIdx.x >> 6;

  __shared__ unsigned short ldsC[32][524];  // 33.5 KB, row stride 1048 B

  const float* __restrict__ src =
      mask_out + (size_t)b * 256 * kHW + (size_t)ks * 32 * kHW + pxt * 256;

#pragma unroll
  for (int i = 0; i < 8; ++i) {
    const int ch = wv * 8 + i;
    const float4 v = *(const float4*)&src[(size_t)ch * kHW + lane * 4];
    uint2 pk;
    pk.x = (unsigned int)f2bf(v.x) | ((unsigned int)f2bf(v.y) << 16);
    pk.y = (unsigned int)f2bf(v.z) | ((unsigned int)f2bf(v.w) << 16);
    *(uint2*)&ldsC[ch][lane * 4] = pk;  // ds_write_b64, 2-way (free)
  }
  __syncthreads();

  const int px16 = lane & 15, kh = lane >> 4;
  unsigned short* __restrict__ dstbase =
      moT + (((size_t)b * 2304 + pxt * 16) * 8 + ks) * 512 + (size_t)lane * 8;
#pragma unroll
  for (int f = 0; f < 4; ++f) {
    const int pxblk = (threadIdx.x >> 6) * 4 + f;  // 0..15 local
    const int px = pxblk * 16 + px16;
    bf16x8 frag;
#pragma unroll
    for (int j = 0; j < 8; ++j) frag[j] = (short)ldsC[kh * 8 + j][px];
    *(bf16x8*)(dstbase + (size_t)pxblk * 4096) = frag;  // 1 KB/wave coalesced
  }
}

// ---------------------------------------------------------------------------
// K2: GEMM + dice (bid < 1152) and focal (tail blocks). GEMM has NO LDS
// staging and NO k-loop barriers: each lane loads its 8 B-frags as
// contiguous dwordx4 from moT (L3-hot), A-frags from L1-hot kbf, 40 MFMAs.
// Fused dice epilogue: sigmoid, mt gather, 16-lane shfl reduce, LDS block
// reduce, one atomic per (row, quantity).
// ---------------------------------------------------------------------------
__global__ __launch_bounds__(256, 4) void gemm_focal_kernel(
    const unsigned short* __restrict__ moT,
    const unsigned short* __restrict__ kbf,
    const float* __restrict__ mask_targets,
    const float* __restrict__ c0, const float* __restrict__ c1,
    const float* __restrict__ c2, const float* __restrict__ c3,
    const float* __restrict__ c4,
    const int* __restrict__ t0, const int* __restrict__ t1,
    const int* __restrict__ t2, const int* __restrict__ t3,
    const int* __restrict__ t4,
    float* __restrict__ acc) {
  __shared__ float bred[4][240];
  const int bid = blockIdx.x;

  if (bid >= kGemmBlocks) {
    // ---------------- focal tail ----------------
    const int idx = (bid - kGemmBlocks) * 256 + threadIdx.x;  // < 154880
    const int n = idx / 20;
    const int cq = (idx - n * 20) * 4;
    int t;
    const float* crow;
    if (n < 3200) {
      t = t0[n]; crow = c0 + (size_t)n * 80;
    } else if (n < 5792) {
      const int o = n - 3200; t = t1[o]; crow = c1 + (size_t)o * 80;
    } else if (n < 6944) {
      const int o = n - 5792; t = t2[o]; crow = c2 + (size_t)o * 80;
    } else if (n < 7456) {
      const int o = n - 6944; t = t3[o]; crow = c3 + (size_t)o * 80;
    } else {
      const int o = n - 7456; t = t4[o]; crow = c4 + (size_t)o * 80;
    }
    float term = 0.f, np = 0.f;
    if (t > -1) {
      const float4 pv4 = *(const float4*)&crow[cq];
      const float pvs[4] = {pv4.x, pv4.y, pv4.z, pv4.w};
#pragma unroll
      for (int j = 0; j < 4; ++j) {
        float pv = fminf(fmaxf(pvs[j], 1e-4f), 1.f - 1e-4f);
        const bool gm = (cq + j == t);
        const float af = gm ? 0.25f : 0.75f;
        const float pt = gm ? pv : 1.f - pv;
        const float om = 1.f - pt;
        term = fmaf(af * om * om, -__logf(pt), term);
      }
      if (cq == 0) np = 1.f;
    }
    term = wave_sum(term);
    np = wave_sum(np);
    const int wid = threadIdx.x >> 6;
    if ((threadIdx.x & 63) == 0) {
      bred[0][wid] = term;
      bred[0][4 + wid] = np;
    }
    __syncthreads();
    if (threadIdx.x == 0) {
      unsafeAtomicAdd(&acc[480],
                      bred[0][0] + bred[0][1] + bred[0][2] + bred[0][3]);
      unsafeAtomicAdd(&acc[481],
                      bred[0][4] + bred[0][5] + bred[0][6] + bred[0][7]);
    }
    return;
  }

  // ---------------- GEMM + dice ----------------
  const int b = bid / 576;
  const int tile = bid - b * 576;
  const int lane = threadIdx.x & 63;
  const int wv = threadIdx.x >> 6;
  const int px16 = lane & 15;
  const int hi8 = (lane >> 4) * 8;
  const int pxblk = tile * 4 + wv;        // global 16-px block
  const int pxl = pxblk * 16 + px16;      // this lane's pixel

  // All 8 B-frags: contiguous 16 B per lane per ks (1 KB per wave-inst).
  const unsigned short* __restrict__ bsrc =
      moT + ((size_t)(b * 2304 + pxblk) * 8) * 512 + (size_t)lane * 8;
  bf16x8 bfr[8];
#pragma unroll
  for (int ks = 0; ks < 8; ++ks)
    bfr[ks] = *(const bf16x8*)(bsrc + (size_t)ks * 512);

  const unsigned short* __restrict__ ka =
      kbf + ((size_t)b * 80 + px16) * 256 + hi8;

  f32x4 a5[5];
#pragma unroll
  for (int mt = 0; mt < 5; ++mt) a5[mt] = (f32x4){0.f, 0.f, 0.f, 0.f};

#pragma unroll
  for (int ks = 0; ks < 8; ++ks) {
#pragma unroll
    for (int mt = 0; mt < 5; ++mt) {
      const bf16x8 af = *(const bf16x8*)(ka + mt * 4096 + ks * 32);
      a5[mt] =
          __builtin_amdgcn_mfma_f32_16x16x32_bf16(af, bfr[ks], a5[mt], 0, 0, 0);
    }
  }

  // D layout (m89): col = lane&15 (pixel), row80 = mt*16 + (lane>>4)*4 + reg.
  // Global flat row r = (row80>>4)*32 + b*16 + (row80&15); pairs with
  // mask_targets flat row r.
#pragma unroll
  for (int mt = 0; mt < 5; ++mt) {
#pragma unroll
    for (int j = 0; j < 4; ++j) {
      const int row80 = mt * 16 + (lane >> 4) * 4 + j;
      const int r = (row80 >> 4) * 32 + b * 16 + (row80 & 15);
      const float mp = 1.f / (1.f + __expf(-a5[mt][j]));
      const float tv = mask_targets[(size_t)r * kHW + pxl];
      float av = mp * tv;
      float bv = mp * mp;
      float cv = tv;  // binary targets: t*t == t
#pragma unroll
      for (int m = 1; m <= 8; m <<= 1) {
        av += __shfl_xor(av, m, 64);
        bv += __shfl_xor(bv, m, 64);
        cv += __shfl_xor(cv, m, 64);
      }
      if (px16 == 0) {
        bred[wv][row80] = av;
        bred[wv][80 + row80] = bv;
        bred[wv][160 + row80] = cv;
      }
    }
  }
  __syncthreads();
  if (threadIdx.x < 240) {
    const int q = threadIdx.x / 80;
    const int row80 = threadIdx.x - q * 80;
    const int r = (row80 >> 4) * 32 + b * 16 + (row80 & 15);
    const float s = bred[0][threadIdx.x] + bred[1][threadIdx.x] +
                    bred[2][threadIdx.x] + bred[3][threadIdx.x];
    unsafeAtomicAdd(&acc[q * 160 + r], s);
  }
}

__global__ __launch_bounds__(64) void finalize_kernel(
    const float* __restrict__ acc, float* __restrict__ out) {
  const int tid = threadIdx.x;
  float s = 0.f;
#pragma unroll
  for (int rr = 0; rr < 3; ++rr) {
    const int r = tid + rr * 64;
    if (r < 160) {
      const float a = acc[r];
      const float bb = acc[160 + r];
      const float cc = acc[320 + r];
      s += 1.f - 2.f * a / (bb + cc + 1e-4f);
    }
  }
  s = wave_sum(s);
  if (tid == 0) {
    out[0] = 3.0f * (s / 160.f);   // MASK_W * mask_loss
    out[1] = acc[480] / acc[481];  // CLS_W * cls_loss
  }
}

}  // namespace

extern "C" void kernel_launch(void* const* d_in, const int* in_sizes, int n_in,
                              void* d_out, int out_size, void* d_ws,
                              size_t ws_size, hipStream_t stream) {
  const float* mask_out = (const float*)d_in[0];
  const float* k[5];
  const float* cc[5];
  const int* pp[5];
  const int* tt[5];
  for (int i = 0; i < 5; ++i) {
    k[i] = (const float*)d_in[1 + 4 * i];
    cc[i] = (const float*)d_in[2 + 4 * i];
    pp[i] = (const int*)d_in[3 + 4 * i];
    tt[i] = (const int*)d_in[4 + 4 * i];
  }
  const float* mt = (const float*)d_in[21];

  char* ws = (char*)d_ws;
  float* acc = (float*)ws;                              // 482 f @ 0
  unsigned short* kbf = (unsigned short*)(ws + 4096);   // 81,920 B
  unsigned short* moT = (unsigned short*)(ws + 90112);  // 37,748,736 B
  float* out = (float*)d_out;

  hipLaunchKernelGGL(repack_prep_kernel, dim3(kRepackBlocks + 161), dim3(256),
                     0, stream, mask_out, k[0], k[1], k[2], k[3], k[4], pp[0],
                     pp[1], pp[2], pp[3], pp[4], moT, kbf, acc);
  hipLaunchKernelGGL(gemm_focal_kernel, dim3(kGemmBlocks + kFocalBlocks),
                     dim3(256), 0, stream, moT, kbf, mt, cc[0], cc[1], cc[2],
                     cc[3], cc[4], tt[0], tt[1], tt[2], tt[3], tt[4], acc);
  hipLaunchKernelGGL(finalize_kernel, dim3(1), dim3(64), 0, stream, acc, out);
}